// Round 2
// baseline (251.521 us; speedup 1.0000x reference)
//
#include <hip/hip_runtime.h>
#include <stdint.h>

#define EPS 1e-3f

typedef __bf16 bf16x8 __attribute__((ext_vector_type(8)));
typedef float  f32x4  __attribute__((ext_vector_type(4)));

static __device__ __forceinline__ uint16_t f2bf(float f) {
  union { float f; uint32_t u; } v; v.f = f;
  uint32_t u = v.u;
  uint32_t r = u + 0x7fffu + ((u >> 16) & 1u);   // RNE
  return (uint16_t)(r >> 16);
}
static __device__ __forceinline__ uint32_t pack2bf(float lo, float hi) {
  union { __bf16 b[2]; uint32_t u; } r;
  r.b[0] = (__bf16)lo; r.b[1] = (__bf16)hi;
  return r.u;
}
static __device__ __forceinline__ void gload_lds16(const void* g, void* l) {
  __builtin_amdgcn_global_load_lds(
      (const __attribute__((address_space(1))) unsigned int*)g,
      (__attribute__((address_space(3))) unsigned int*)l, 16, 0, 0);
}

// ---------------------------------------------------------------------------
// Kernel 1: projections + BN(q,v) + softmax(k).  x:[16384][256]
// 64 rows/block, W-loads amortized over 4 rows/thread.
// ---------------------------------------------------------------------------
__global__ __launch_bounds__(256) void proj_kernel(
    const float* __restrict__ x, const float* __restrict__ Wq,
    const float* __restrict__ Wk, const float* __restrict__ Wv,
    const float* __restrict__ gq, const float* __restrict__ bq,
    const float* __restrict__ mq, const float* __restrict__ vq,
    const float* __restrict__ gv, const float* __restrict__ bv,
    const float* __restrict__ mv, const float* __restrict__ vvp,
    float* __restrict__ Qf, float* __restrict__ Ksm, float* __restrict__ Vf)
{
  __shared__ float xs[64 * 260];
  const int t = threadIdx.x;
  const int r0 = blockIdx.x * 64;
#pragma unroll
  for (int it = 0; it < 16; ++it) {
    int f = it * 256 + t;
    int row = f >> 6, c4 = f & 63;
    *(float4*)&xs[row * 260 + c4 * 4] =
        *(const float4*)&x[(size_t)(r0 + row) * 256 + c4 * 4];
  }
  __syncthreads();
  const int rg = t >> 4, ci = t & 15;
  const float* xr = xs + rg * 4 * 260;

  float aq[4][4], ak[4], av[4][4];
#pragma unroll
  for (int rr = 0; rr < 4; ++rr) {
    ak[rr] = 0.f;
#pragma unroll
    for (int j = 0; j < 4; ++j) { aq[rr][j] = 0.f; av[rr][j] = 0.f; }
  }

#pragma unroll 2
  for (int m = 0; m < 256; ++m) {
    float w0 = Wq[m * 64 + ci];
    float w1 = Wq[m * 64 + ci + 16];
    float w2 = Wq[m * 64 + ci + 32];
    float w3 = Wq[m * 64 + ci + 48];
    float wk = Wk[m * 16 + ci];
    float u0 = Wv[m * 64 + ci];
    float u1 = Wv[m * 64 + ci + 16];
    float u2 = Wv[m * 64 + ci + 32];
    float u3 = Wv[m * 64 + ci + 48];
#pragma unroll
    for (int rr = 0; rr < 4; ++rr) {
      float xv = xr[rr * 260 + m];
      aq[rr][0] = fmaf(xv, w0, aq[rr][0]);
      aq[rr][1] = fmaf(xv, w1, aq[rr][1]);
      aq[rr][2] = fmaf(xv, w2, aq[rr][2]);
      aq[rr][3] = fmaf(xv, w3, aq[rr][3]);
      ak[rr]    = fmaf(xv, wk, ak[rr]);
      av[rr][0] = fmaf(xv, u0, av[rr][0]);
      av[rr][1] = fmaf(xv, u1, av[rr][1]);
      av[rr][2] = fmaf(xv, u2, av[rr][2]);
      av[rr][3] = fmaf(xv, u3, av[rr][3]);
    }
  }

  // hoisted BN params (depend only on column)
  float sqv[4], bqv[4], mqv[4], svv[4], bvv[4], mvv[4];
#pragma unroll
  for (int j = 0; j < 4; ++j) {
    int c = ci + 16 * j;
    sqv[j] = gq[c] * rsqrtf(vq[c] + EPS); bqv[j] = bq[c]; mqv[j] = mq[c];
    svv[j] = gv[c] * rsqrtf(vvp[c] + EPS); bvv[j] = bv[c]; mvv[j] = mv[c];
  }

#pragma unroll
  for (int rr = 0; rr < 4; ++rr) {
    const int r = r0 + rg * 4 + rr;
#pragma unroll
    for (int j = 0; j < 4; ++j)
      Qf[(size_t)r * 64 + ci + 16 * j] = (aq[rr][j] - mqv[j]) * sqv[j] + bqv[j];
    // softmax over the 16 channels held by the 16 lanes of this row group
    float kv = ak[rr];
    float mx = kv;
#pragma unroll
    for (int d = 1; d < 16; d <<= 1) mx = fmaxf(mx, __shfl_xor(mx, d, 64));
    float e = __expf(kv - mx);
    float sm = e;
#pragma unroll
    for (int d = 1; d < 16; d <<= 1) sm += __shfl_xor(sm, d, 64);
    Ksm[(size_t)r * 16 + ci] = e / sm;
#pragma unroll
    for (int j = 0; j < 4; ++j)
      Vf[(size_t)r * 64 + ci + 16 * j] = (av[rr][j] - mvv[j]) * svv[j] + bvv[j];
  }
}

// ---------------------------------------------------------------------------
// Kernel 2: V transpose+convert.  Vf:[b*1024+m][64] -> VbfT:[b*64+v][1024 m]
// ---------------------------------------------------------------------------
__global__ __launch_bounds__(256) void transpose_v(const float* __restrict__ Vf,
                                                   uint16_t* __restrict__ VbfT)
{
  __shared__ float tile[64][65];
  const int b = blockIdx.x, mc = blockIdx.y, t = threadIdx.x;
  const int m0 = mc * 64;
#pragma unroll
  for (int it = 0; it < 4; ++it) {
    int off = it * 1024 + t * 4;
    int ml = off >> 6, v = off & 63;
    float4 d = *(const float4*)&Vf[(size_t)(b * 1024 + m0 + ml) * 64 + v];
    tile[ml][v + 0] = d.x; tile[ml][v + 1] = d.y;
    tile[ml][v + 2] = d.z; tile[ml][v + 3] = d.w;
  }
  __syncthreads();
  const int v = t >> 2, sg = t & 3;
  union { uint16_t u16[16]; uint4 u4[2]; } pk;
#pragma unroll
  for (int i = 0; i < 16; ++i) pk.u16[i] = f2bf(tile[sg * 16 + i][v]);
  uint4* dst = (uint4*)&VbfT[(size_t)(b * 64 + v) * 1024 + m0 + sg * 16];
  dst[0] = pk.u4[0]; dst[1] = pk.u4[1];
}

// ---------------------------------------------------------------------------
// Kernel 3a: lam_c partials.  grid (16 b, 16 m-chunks)
// part[b][mc][k][v] = sum_{m in chunk} Ksm[b,m,k] * Vf[b,m,v]
// ---------------------------------------------------------------------------
__global__ __launch_bounds__(256) void lamc_part(const float* __restrict__ Ksm,
                                                 const float* __restrict__ Vf,
                                                 float* __restrict__ part)
{
  __shared__ float ks[64][20];
  const int b = blockIdx.x, mc = blockIdx.y, t = threadIdx.x;
  const int m0 = mc * 64;
  {
    int ml = t >> 2, kk = (t & 3) * 4;
    *(float4*)&ks[ml][kk] =
        *(const float4*)&Ksm[(size_t)(b * 1024 + m0 + ml) * 16 + kk];
  }
  __syncthreads();
  const int kqq = t >> 6, v = t & 63;
  float a0 = 0.f, a1 = 0.f, a2 = 0.f, a3 = 0.f;
#pragma unroll 4
  for (int ml = 0; ml < 64; ++ml) {
    float vv = Vf[(size_t)(b * 1024 + m0 + ml) * 64 + v];
    a0 = fmaf(ks[ml][kqq * 4 + 0], vv, a0);
    a1 = fmaf(ks[ml][kqq * 4 + 1], vv, a1);
    a2 = fmaf(ks[ml][kqq * 4 + 2], vv, a2);
    a3 = fmaf(ks[ml][kqq * 4 + 3], vv, a3);
  }
  float* dst = part + (size_t)(b * 16 + mc) * 1024 + (kqq * 4) * 64 + v;
  dst[0] = a0; dst[64] = a1; dst[128] = a2; dst[192] = a3;
}

// Kernel 3b: reduce 16 partials -> Lc[b][k][v]
__global__ __launch_bounds__(256) void lamc_reduce(const float* __restrict__ part,
                                                   float* __restrict__ Lc)
{
  const int gid = blockIdx.x * 256 + threadIdx.x;   // 0..16383
  const int b = gid >> 10, r = gid & 1023;
  const float* p = part + ((size_t)b << 14) + r;    // b*16*1024
  float s = 0.f;
#pragma unroll
  for (int mc = 0; mc < 16; ++mc) s += p[mc * 1024];
  Lc[((size_t)b << 10) + r] = s;
}

// ---------------------------------------------------------------------------
// Kernel 4: GEMM C[row=n*16+k][col=b*64+v] = E . VbfT  (A converted in-kernel)
// 256x256 tile, BK=64, 8 waves (2x4), double-buffered prefetch, XCD swizzle.
// Fused epilogue: out = Q-contraction of (C + Lc).
// ---------------------------------------------------------------------------
__global__ __launch_bounds__(512, 2) void gemm_out(
    const float* __restrict__ E,        // [1024 n][1024 m][16 k] f32
    const uint16_t* __restrict__ VbfT,  // [1024 col][1024 m] bf16
    const float* __restrict__ Qf,       // [16384][64]
    const float* __restrict__ Lc,       // [16][16][64]
    float* __restrict__ out)            // [16384][256]
{
  __shared__ __align__(16) char smem[131072];
  const int t = threadIdx.x;
  const int wid = t >> 6, lane = t & 63;
  const int wm = wid >> 2, wn = wid & 3;
  const int bid = blockIdx.x;
  const int rb = (bid & 7) * 8 + ((bid >> 3) >> 2);   // XCD-grouped
  const int cb = (bid >> 3) & 3;
  const int n0 = rb * 16;
  const int col0 = cb * 256;

  const int kq = t & 3;          // which k-quad this thread loads
  const int mp = (t >> 2) & 31;  // m-pair index
  const int nb = t >> 7;         // 0..3

  f32x4 acc[8][4];
#pragma unroll
  for (int i = 0; i < 8; ++i)
#pragma unroll
    for (int j = 0; j < 4; ++j) acc[i][j] = f32x4{0.f, 0.f, 0.f, 0.f};

  const float* Eb = E + ((size_t)n0 << 14);
  const uint16_t* Bg = VbfT + ((size_t)col0 << 10);

  char* const Ab0 = smem;
  char* const Ab1 = smem + 32768;
  char* const Bb0 = smem + 65536;
  char* const Bb1 = smem + 98304;

  float4 ra[4], rbx[4];

  // ---- prologue: tile 0 ----
#pragma unroll
  for (int it = 0; it < 4; ++it) {
    size_t base = ((size_t)(it * 4 + nb) << 14) + ((size_t)(mp * 2) << 4) + (kq << 2);
    ra[it]  = *(const float4*)(Eb + base);
    rbx[it] = *(const float4*)(Eb + base + 16);
  }
#pragma unroll
  for (int it = 0; it < 4; ++it) {
    int idx = it * 512 + t;
    int row = idx >> 3, seg = idx & 7;
    gload_lds16(Bg + ((size_t)row << 10) + ((seg ^ (row & 7)) << 3), Bb0 + idx * 16);
  }
#pragma unroll
  for (int it = 0; it < 4; ++it) {
    const float* da = (const float*)&ra[it];
    const float* db = (const float*)&rbx[it];
#pragma unroll
    for (int j = 0; j < 4; ++j) {
      int row = (it * 4 + nb) * 16 + kq * 4 + j;
      *(uint32_t*)(Ab0 + row * 128 + ((mp * 4) ^ ((row & 7) << 4))) =
          pack2bf(da[j], db[j]);
    }
  }
  __syncthreads();

  // ---- main loop: 16 K-tiles of 64 ----
#pragma unroll 1
  for (int kt = 0; kt < 16; ++kt) {
    const int cur = kt & 1;
    char* Ac = cur ? Ab1 : Ab0;
    char* Bc = cur ? Bb1 : Bb0;
    char* An = cur ? Ab0 : Ab1;
    char* Bn = cur ? Bb0 : Bb1;
    const int m0n = (kt + 1) * 64;
    if (kt < 15) {
#pragma unroll
      for (int it = 0; it < 4; ++it) {
        size_t base = ((size_t)(it * 4 + nb) << 14) +
                      ((size_t)(m0n + mp * 2) << 4) + (kq << 2);
        ra[it]  = *(const float4*)(Eb + base);
        rbx[it] = *(const float4*)(Eb + base + 16);
      }
#pragma unroll
      for (int it = 0; it < 4; ++it) {
        int idx = it * 512 + t;
        int row = idx >> 3, seg = idx & 7;
        gload_lds16(Bg + ((size_t)row << 10) + m0n + ((seg ^ (row & 7)) << 3),
                    Bn + idx * 16);
      }
    }
    // compute current tile
#pragma unroll
    for (int kk = 0; kk < 2; ++kk) {
      bf16x8 a[8], b[4];
      const int s = kk * 4 + (lane >> 4);
#pragma unroll
      for (int i = 0; i < 8; ++i) {
        int row = wm * 128 + i * 16 + (lane & 15);
        a[i] = *(const bf16x8*)(Ac + row * 128 + ((s ^ (row & 7)) << 4));
      }
#pragma unroll
      for (int j = 0; j < 4; ++j) {
        int row = wn * 64 + j * 16 + (lane & 15);
        b[j] = *(const bf16x8*)(Bc + row * 128 + ((s ^ (row & 7)) << 4));
      }
#pragma unroll
      for (int i = 0; i < 8; ++i)
#pragma unroll
        for (int j = 0; j < 4; ++j)
          acc[i][j] = __builtin_amdgcn_mfma_f32_16x16x32_bf16(a[i], b[j], acc[i][j], 0, 0, 0);
    }
    // write next A tile (loads have drained behind the MFMAs)
    if (kt < 15) {
#pragma unroll
      for (int it = 0; it < 4; ++it) {
        const float* da = (const float*)&ra[it];
        const float* db = (const float*)&rbx[it];
#pragma unroll
        for (int j = 0; j < 4; ++j) {
          int row = (it * 4 + nb) * 16 + kq * 4 + j;
          *(uint32_t*)(An + row * 128 + ((mp * 4) ^ ((row & 7) << 4))) =
              pack2bf(da[j], db[j]);
        }
      }
    }
    __syncthreads();
  }

  // ---- fused epilogue: 4 phases of 64 rows through LDS ----
  float* Cs = (float*)smem;        // [64][258]
  const int b0 = cb * 4;
#pragma unroll 1
  for (int p = 0; p < 4; ++p) {
    if (wm == (p >> 1)) {
#pragma unroll
      for (int il = 0; il < 4; ++il) {
        const int i = ((p & 1) << 2) + il;
#pragma unroll
        for (int j = 0; j < 4; ++j) {
          const int col = wn * 64 + j * 16 + (lane & 15);
          const int bb = b0 + (col >> 6), v = col & 63;
#pragma unroll
          for (int r = 0; r < 4; ++r) {
            const int rl = il * 16 + ((lane >> 4) << 2) + r;
            const int k = rl & 15;
            Cs[rl * 258 + col] = acc[i][j][r] + Lc[(size_t)(((bb << 4) + k) << 6) + v];
          }
        }
      }
    }
    __syncthreads();
    {
      const int v = t & 63;
#pragma unroll
      for (int c = 0; c < 8; ++c) {
        const int combo = (wid << 3) + c;               // 0..63
        const int n_l = combo >> 4;
        const int b_l = (combo >> 2) & 3;
        const int h = combo & 3;
        const int n = n0 + (p << 2) + n_l;
        const int bb = b0 + b_l;
        const float* qp = Qf + (((size_t)(bb << 10) + n) << 6) + (h << 4);
        float sum = 0.f;
#pragma unroll
        for (int k = 0; k < 16; ++k)
          sum = fmaf(qp[k], Cs[((n_l << 4) + k) * 258 + (b_l << 6) + v], sum);
        out[(((size_t)(bb << 10) + n) << 8) + (h << 6) + v] = sum;
      }
    }
    __syncthreads();
  }
}

// ---------------------------------------------------------------------------
extern "C" void kernel_launch(void* const* d_in, const int* in_sizes, int n_in,
                              void* d_out, int out_size, void* d_ws, size_t ws_size,
                              hipStream_t stream) {
  const float* x   = (const float*)d_in[0];
  const float* Wq  = (const float*)d_in[1];
  const float* Wk  = (const float*)d_in[2];
  const float* Wv  = (const float*)d_in[3];
  const float* gq  = (const float*)d_in[4];
  const float* bq  = (const float*)d_in[5];
  const float* mq  = (const float*)d_in[6];
  const float* vq  = (const float*)d_in[7];
  const float* gv  = (const float*)d_in[8];
  const float* bv  = (const float*)d_in[9];
  const float* mv  = (const float*)d_in[10];
  const float* vvp = (const float*)d_in[11];
  const float* E   = (const float*)d_in[12];
  float* out = (float*)d_out;

  char* ws = (char*)d_ws;
  uint16_t* VbfT = (uint16_t*)(ws);                       // 2 MB
  float*    Qf   = (float*)(ws + (size_t)(2 << 20));      // 4 MB
  float*    Ksm  = (float*)(ws + (size_t)(6 << 20));      // 1 MB
  float*    Vf   = (float*)(ws + (size_t)(7 << 20));      // 4 MB
  float*    Lc   = (float*)(ws + (size_t)(11 << 20));     // 64 KB
  float*    part = (float*)(ws + (size_t)(11 << 20) + 65536);  // 1 MB

  hipLaunchKernelGGL(proj_kernel, dim3(256), dim3(256), 0, stream, x, Wq, Wk, Wv,
                     gq, bq, mq, vq, gv, bv, mv, vvp, Qf, Ksm, Vf);
  hipLaunchKernelGGL(transpose_v, dim3(16, 16), dim3(256), 0, stream, Vf, VbfT);
  hipLaunchKernelGGL(lamc_part, dim3(16, 16), dim3(256), 0, stream, Ksm, Vf, part);
  hipLaunchKernelGGL(lamc_reduce, dim3(64), dim3(256), 0, stream, part, Lc);
  hipLaunchKernelGGL(gemm_out, dim3(256), dim3(512), 0, stream, E, VbfT, Qf, Lc, out);
}